// Round 6
// baseline (174.128 us; speedup 1.0000x reference)
//
#include <hip/hip_runtime.h>
#include <hip/hip_bf16.h>
#include <hip/hip_fp8.h>
#include <stdint.h>

// Shapes: b=2, n=5, k=5, q=75, t=196, c=384, s=k*t=980 (padded to 1024/class)
// M per b = 75*196 = 14700 (58 tiles of 256 rows). Outputs: logits[750] ++ cls_logits[750].
// Sim branch: fp8-e4m3 MX-scaled MFMA (scales=1.0); cls branch exact fp32.
//
// Round-15: R13 inner loop (the proven best: depth-3 16x16x128 register pipeline,
// 8 independent acc chains, no LDS/barriers, 62us) + K-SPLIT for tail quantization.
// R14 post-mortem: 32x32x64 collapsed 8 acc chains -> 2, VALUBusy 19->31 (f32x16/AGPR
// shuffling), 62->78us. Reverted.
// R13's remaining structural loss: 1160 blocks x 4 waves = 4640 equal-length waves; at
// 2-3 waves/SIMD residency (2048-3072 concurrent) the machine runs 2.x "rounds" + a
// 27%-fill tail -> ~75% scheduling efficiency, matching MfmaUtil 36% vs ~48% resident.
// Fix: split each (bc,sh) panel's 16 chunks into 2 ksub halves of 8 -> 2320 blocks of
// half-length waves (span 2.5T/2 vs 3T at 2/SIMD; 1.75 vs 2 at 3/SIMD). P merges via
// the existing atomicMax. Bonus: sh=1/ksub=1 runs chunks 8..14 only (chunk 15 = cols
// 992..1023 is all padding) -> -3% MFMA work. Cost: A prologue 2x (~4%).

typedef __attribute__((ext_vector_type(8))) int int8v;      // f8f6f4 A/B operand (32 fp8)
typedef __attribute__((ext_vector_type(4))) float f32x4;    // MFMA C/D frag

__device__ __forceinline__ unsigned enc_f(float f) {
    unsigned b = __float_as_uint(f);
    return (b & 0x80000000u) ? ~b : (b | 0x80000000u);
}
__device__ __forceinline__ float dec_f(unsigned u) {
    unsigned b = (u & 0x80000000u) ? (u & 0x7FFFFFFFu) : ~u;
    return __uint_as_float(b);
}

__device__ __forceinline__ unsigned pack4_fp8(float a, float b, float c, float d) {
    int r = __builtin_amdgcn_cvt_pk_fp8_f32(a, b, 0, false);   // bytes 0,1
    r = __builtin_amdgcn_cvt_pk_fp8_f32(c, d, r, true);        // bytes 2,3
    return (unsigned)r;
}

// ---------------- fused prep: norm (16 lanes/row) | proto | init_P ----------------
// Query rows -> fqn row-major [tr][96 words]. Shot rows -> fsnp in FRAGMENT order:
// word addr = bn*98304 + sh*49152 + chunk*3072 + ks*1024 + part*256 + hi*64 + l15*4 + w
// where (per j, lane-l16): ks=j>>1, part=(l16>>2)&1, hi=(j&1)*2+(l16>>3), w=l16&3.
__global__ void prep_kernel(const float* __restrict__ feat_query,
                            const float* __restrict__ feat_shot,
                            const float* __restrict__ x_shot,
                            unsigned* __restrict__ fqn,
                            unsigned* __restrict__ fsnp,
                            float* __restrict__ proto,
                            unsigned* __restrict__ P) {
    const int blk  = blockIdx.x;
    const int tid  = threadIdx.x;
    const int lane = tid & 63;
    const int wv   = tid >> 6;

    if (blk < 2478) {                       // ---- token L2 norm -> fp8, 4 rows/wave ----
        const int tr  = blk * 16 + wv * 4 + (lane >> 4);   // 0..39639
        const int l16 = lane & 15;
        if (tr >= 39640) return;

        const float* row;
        unsigned* o32;
        bool zero = false;
        bool shot = false;
        if (tr < 29400) {
            row = feat_query + (size_t)tr * 384;
            o32 = fqn + (size_t)tr * 96;
        } else {
            const int sp = tr - 29400;          // padded shot row: [bn][1024]
            const int bn = sp >> 10;
            const int s  = sp & 1023;           // col within class block
            row  = feat_shot + ((size_t)bn * 980 + s) * 384;
            zero = (s >= 980);
            shot = true;
            const int shh   = s >> 9;
            const int c     = s & 511;
            const int chunk = c >> 5;
            const int cl    = c & 31;
            o32 = fsnp + (size_t)bn * 98304 + shh * 49152 + chunk * 3072
                       + (cl >> 4) * 512 + (cl & 15) * 4;
        }
        // per-j store index (fragment order for shot, row-major for query)
        int idxs[6];
#pragma unroll
        for (int j = 0; j < 6; ++j)
            idxs[j] = shot ? ((j >> 1) * 1024 + ((l16 >> 2) & 1) * 256
                              + (((j & 1) << 1) + (l16 >> 3)) * 64 + (l16 & 3))
                           : (l16 + 16 * j);

        if (zero) {
#pragma unroll
            for (int j = 0; j < 6; ++j) o32[idxs[j]] = 0u;
            return;
        }
        const float4* rf4 = (const float4*)row;
        float4 v[6];
        float ss = 0.f;
#pragma unroll
        for (int j = 0; j < 6; ++j) {
            v[j] = rf4[l16 + 16 * j];
            ss += v[j].x * v[j].x + v[j].y * v[j].y + v[j].z * v[j].z + v[j].w * v[j].w;
        }
#pragma unroll
        for (int off = 1; off < 16; off <<= 1) ss += __shfl_xor(ss, off, 64);
        const float sc = 1.0f / fmaxf(sqrtf(ss), 1e-8f);
#pragma unroll
        for (int j = 0; j < 6; ++j)
            o32[idxs[j]] = pack4_fp8(v[j].x * sc, v[j].y * sc, v[j].z * sc, v[j].w * sc);
    } else if (blk < 2481) {                // ---- proto = l2norm(mean_k x_shot), fp32 ----
        const int gw = (blk - 2478) * 4 + wv;
        if (gw >= 10) return;
        const float* base = x_shot + (size_t)gw * 5 * 384;
        float v[6];
        float ss = 0.f;
#pragma unroll
        for (int j = 0; j < 6; ++j) {
            float s = 0.f;
#pragma unroll
            for (int kk = 0; kk < 5; ++kk) s += base[kk * 384 + lane + 64 * j];
            s *= 0.2f;
            v[j] = s;
            ss += s * s;
        }
#pragma unroll
        for (int off = 1; off < 64; off <<= 1) ss += __shfl_xor(ss, off, 64);
        const float scale = 1.0f / fmaxf(sqrtf(ss), 1e-12f);
#pragma unroll
        for (int j = 0; j < 6; ++j) proto[(size_t)gw * 384 + lane + 64 * j] = v[j] * scale;
    } else {                                // ---- init P to encoded -inf (0) ----
        const int i = (blk - 2481) * 256 + tid;
        if (i < 147000) P[i] = 0u;
    }
}

// ---------------- fp8 GEMM + row-max: 256 A-rows in regs, B depth-3 pipelined ----------------
// grid = 2b x 5cls x 2sh x 2ksub x 58mt = 2320 blocks; 256 thr = 4 waves (64 rows each).
// Each block covers 8 chunks (ksub half of the 512-col sh panel); sh=1/ksub=1 covers 7
// (chunk 15 is all padding). No LDS, no barriers. B streams from the fragment-ordered
// fsnp (coalesced 1KB dwordx4 loads) through a rolling 3-slot register pipeline: slot
// ks holds local k-step k with k%3==ks; after the 8 MFMAs of k-step k the slot is
// re-issued for k+3 (WAR on the same regs keeps pressure flat; indices compile-time).
__global__ __launch_bounds__(256, 2) void gemm_kernel(const uint8_t* __restrict__ fqn,
                                                      const uint8_t* __restrict__ fsnp,
                                                      unsigned* __restrict__ P) {
    const int bid = blockIdx.x;       // ((((b*5+cls)*2+sh)*2)+ksub)*58 + mt
    const int mt  = bid % 58;
    const int g1  = bid / 58;
    const int ksub= g1 & 1;
    const int sh  = (g1 >> 1) & 1;
    const int bc  = g1 >> 2;          // b*5+cls
    const int b   = bc / 5;
    const int m0  = mt * 256;

    const int tid  = threadIdx.x;
    const int lane = tid & 63;
    const int wv   = tid >> 6;
    const int l15  = lane & 15;
    const int hi   = lane >> 4;

    // chunk range [c0, c1) within this sh panel; sh=1 chunk 15 is 100% padding
    const int c0 = ksub * 8;
    const int c1 = (sh == 1 && ksub == 1) ? 15 : (ksub + 1) * 8;
    const int nchunks = c1 - c0;
    const int nks = nchunks * 3;

    const uint8_t* Ag = fqn  + (size_t)b * 14700 * 384;
    const uint8_t* Bg = fsnp + (size_t)bc * 393216 + (size_t)sh * 196608;
    const uint8_t* bp = Bg + (size_t)c0 * 12288 + lane * 16;   // + k*4096 + j*1024

    // ---- A fragments -> registers (one-time; wave wv holds rows m0+wv*64 .. +63) ----
    int8v A[4][3];
#pragma unroll
    for (int mi = 0; mi < 4; ++mi) {
        int row = m0 + wv * 64 + mi * 16 + l15;
        row = row < 14700 ? row : 14699;           // clamp; dead rows masked at epilogue
        const uint8_t* pa = Ag + (size_t)row * 384 + hi * 32;
#pragma unroll
        for (int ks = 0; ks < 3; ++ks) {
            const uint4 x = *(const uint4*)(pa + ks * 128);
            const uint4 y = *(const uint4*)(pa + ks * 128 + 16);
            A[mi][ks] = (int8v){(int)x.x, (int)x.y, (int)x.z, (int)x.w,
                                (int)y.x, (int)y.y, (int)y.z, (int)y.w};
        }
    }

    float rmax[4][4];
#pragma unroll
    for (int mi = 0; mi < 4; ++mi)
#pragma unroll
        for (int i = 0; i < 4; ++i) rmax[mi][i] = -3.0e38f;

    // ---- prologue: fill the 3-slot pipeline with local k-steps 0,1,2 ----
    uint4 S[3][4];                          // statically indexed only
#pragma unroll
    for (int ks = 0; ks < 3; ++ks) {
        const uint8_t* p = bp + (size_t)ks * 4096;
#pragma unroll
        for (int j = 0; j < 4; ++j)
            S[ks][j] = *(const uint4*)(p + j * 1024);
    }

    for (int lc = 0; lc < nchunks; ++lc) {
        f32x4 acc[4][2];
#pragma unroll
        for (int mi = 0; mi < 4; ++mi)
#pragma unroll
            for (int nf = 0; nf < 2; ++nf) acc[mi][nf] = (f32x4){0.f, 0.f, 0.f, 0.f};

#pragma unroll
        for (int ks = 0; ks < 3; ++ks) {
            // consume slot ks (local k-step lc*3+ks; lc*3+ks ≡ ks mod 3)
            const int8v Bf0 = (int8v){(int)S[ks][0].x, (int)S[ks][0].y,
                                      (int)S[ks][0].z, (int)S[ks][0].w,
                                      (int)S[ks][1].x, (int)S[ks][1].y,
                                      (int)S[ks][1].z, (int)S[ks][1].w};
            const int8v Bf1 = (int8v){(int)S[ks][2].x, (int)S[ks][2].y,
                                      (int)S[ks][2].z, (int)S[ks][2].w,
                                      (int)S[ks][3].x, (int)S[ks][3].y,
                                      (int)S[ks][3].z, (int)S[ks][3].w};
#pragma unroll
            for (int mi = 0; mi < 4; ++mi) {
                acc[mi][0] = __builtin_amdgcn_mfma_scale_f32_16x16x128_f8f6f4(
                    A[mi][ks], Bf0, acc[mi][0],
                    0, 0, 0, 0x7F7F7F7F, 0, 0x7F7F7F7F);
                acc[mi][1] = __builtin_amdgcn_mfma_scale_f32_16x16x128_f8f6f4(
                    A[mi][ks], Bf1, acc[mi][1],
                    0, 0, 0, 0x7F7F7F7F, 0, 0x7F7F7F7F);
            }
            // re-issue slot ks for local k-step lc*3+ks+3 (clamped tail; issue->use
            // window = 2 full k-steps of MFMA >= loaded L2 latency)
            {
                const int kn = lc * 3 + ks + 3;
                const int kc = kn < nks ? kn : nks - 1;
                const uint8_t* p = bp + (size_t)kc * 4096;
#pragma unroll
                for (int j = 0; j < 4; ++j)
                    S[ks][j] = *(const uint4*)(p + j * 1024);
            }
        }

        // fold row-max (mask padded cols >= 980; only sh=1 late chunks can fail)
        const int ch = c0 + lc;
#pragma unroll
        for (int nf = 0; nf < 2; ++nf) {
            if (sh * 512 + ch * 32 + nf * 16 + l15 < 980) {
#pragma unroll
                for (int mi = 0; mi < 4; ++mi)
#pragma unroll
                    for (int i = 0; i < 4; ++i)
                        rmax[mi][i] = fmaxf(rmax[mi][i], acc[mi][nf][i]);
            }
        }
    }

    // ---- epilogue: max over the 16 col-lanes, then device-scope atomicMax ----
#pragma unroll
    for (int mi = 0; mi < 4; ++mi)
#pragma unroll
        for (int i = 0; i < 4; ++i) {
            float v = rmax[mi][i];
#pragma unroll
            for (int off = 1; off < 16; off <<= 1) v = fmaxf(v, __shfl_xor(v, off, 64));
            if (l15 == 0) {
                const int row = m0 + wv * 64 + mi * 16 + hi * 4 + i;
                if (row < 14700)
                    atomicMax(&P[(size_t)bc * 14700 + row], enc_f(v));
            }
        }
}

// ---------------- fused final: logits (mean over t of row maxima) | cls_logits ----------------
__global__ void final_kernel(const unsigned* __restrict__ P,
                             const float* __restrict__ xq,
                             const float* __restrict__ proto,
                             float* __restrict__ out) {
    const int blk  = blockIdx.x;
    const int tid  = threadIdx.x;
    const int lane = tid & 63;
    const int wv   = tid >> 6;

    if (blk < 188) {                        // ---- logits ----
        const int gw = blk * 4 + wv;        // (b*75+q)*5+n
        if (gw >= 750) return;
        const int n  = gw % 5;
        const int bq = gw / 5;
        const int b  = bq / 75;
        const int q  = bq % 75;
        const unsigned* row = P + (size_t)(b * 5 + n) * 14700 + q * 196;
        float s = 0.f;
        for (int t = lane; t < 196; t += 64) s += dec_f(row[t]);
#pragma unroll
        for (int off = 1; off < 64; off <<= 1) s += __shfl_xor(s, off, 64);
        if (lane == 0) out[gw] = s * (1.0f / 196.0f);
    } else {                                // ---- cls_logits ----
        const int gw = (blk - 188) * 4 + wv;   // b*75+q
        if (gw >= 150) return;
        const float* row = xq + (size_t)gw * 384;
        float u[6];
        float ss = 0.f;
#pragma unroll
        for (int j = 0; j < 6; ++j) { u[j] = row[lane + 64 * j]; ss += u[j] * u[j]; }
#pragma unroll
        for (int off = 1; off < 64; off <<= 1) ss += __shfl_xor(ss, off, 64);
        const float scale = 1.0f / fmaxf(sqrtf(ss), 1e-12f);
#pragma unroll
        for (int j = 0; j < 6; ++j) u[j] *= scale;
        const int b = gw / 75;
        for (int n = 0; n < 5; ++n) {
            const float* p = proto + (size_t)(b * 5 + n) * 384;
            float d = 0.f;
#pragma unroll
            for (int j = 0; j < 6; ++j) d += u[j] * p[lane + 64 * j];
#pragma unroll
            for (int off = 1; off < 64; off <<= 1) d += __shfl_xor(d, off, 64);
            if (lane == 0) out[750 + gw * 5 + n] = 10.0f * d;
        }
    }
}

extern "C" void kernel_launch(void* const* d_in, const int* in_sizes, int n_in,
                              void* d_out, int out_size, void* d_ws, size_t ws_size,
                              hipStream_t stream) {
    const float* feat_shot  = (const float*)d_in[0];  // [2,5,5,196,384]
    const float* feat_query = (const float*)d_in[1];  // [2,75,196,384]
    const float* x_shot     = (const float*)d_in[2];  // [2,5,5,384]
    const float* x_query    = (const float*)d_in[3];  // [2,75,384]
    float* out = (float*)d_out;
    char* ws = (char*)d_ws;

    // ws layout (15.8 MiB total)
    uint8_t*  fqn   = (uint8_t*)ws;                     // 29400*384  = 11,289,600 B (fp8, row-major)
    uint8_t*  fsnp  = (uint8_t*)(ws + 11289600);        // 10240*384  =  3,932,160 B (fp8, FRAGMENT order)
    float*    proto = (float*)(ws + 15221760);          //      3,840 f32
    unsigned* P     = (unsigned*)(ws + 15237120);       //    147,000 u32

    prep_kernel<<<3056, 256, 0, stream>>>(feat_query, feat_shot, x_shot,
                                          (unsigned*)fqn, (unsigned*)fsnp, proto, P);
    gemm_kernel<<<2320, 256, 0, stream>>>(fqn, fsnp, P);
    final_kernel<<<226, 256, 0, stream>>>(P, x_query, proto, out);
}

// Round 7
// 151.885 us; speedup vs baseline: 1.1464x; 1.1464x over previous
//
#include <hip/hip_runtime.h>
#include <hip/hip_bf16.h>
#include <hip/hip_fp8.h>
#include <stdint.h>

// Shapes: b=2, n=5, k=5, q=75, t=196, c=384, s=k*t=980 (padded to 1024/class)
// M per b = 75*196 = 14700 (58 tiles of 256 rows). Outputs: logits[750] ++ cls_logits[750].
// Sim branch: fp8-e4m3 MX-scaled MFMA (scales=1.0); cls branch exact fp32.
//
// Round-16: R13 inner loop restored EXACTLY (depth-3 16x16x128 register pipeline,
// 8 independent acc chains, no LDS/barriers, compile-time 16-chunk loop = 62us best)
// + XCD-chunked reuse-aware block ordering.
// R15 post-mortem: k-split's runtime loop bounds de-unrolled the chunk loop (VGPR 116,
// VALU 30%) and doubled per-block fixed costs + atomic WRITE -> 86.5us. Reverted.
// R13's stall model: 684 cyc/k-step/SIMD wall vs 69 cyc MFMA issue; FETCH 42MB of
// 342MB demand = ~12% L2 misses at L3/HBM latency (600-900cyc). Default round-robin
// scatters the 58 blocks sharing a B-panel and the 10 sharing an A-tile across all
// 8 XCDs -> per-XCD working set ~6MB > 4MB L2, everything refetched.
// Fix: logical w = (b*58+mt)*10 + (cls*2+sh) (A-tile sharers adjacent; one XCD chunk
// = one b's 10 B-half-panels 1.96MB + ~14 A-tiles 1.4MB < 4MB L2); physical bid p ->
// chunk p%8 (XCD via round-robin), position p>>3. Bijective: 1160 = 8*145.

typedef __attribute__((ext_vector_type(8))) int int8v;      // f8f6f4 A/B operand (32 fp8)
typedef __attribute__((ext_vector_type(4))) float f32x4;    // MFMA C/D frag

__device__ __forceinline__ unsigned enc_f(float f) {
    unsigned b = __float_as_uint(f);
    return (b & 0x80000000u) ? ~b : (b | 0x80000000u);
}
__device__ __forceinline__ float dec_f(unsigned u) {
    unsigned b = (u & 0x80000000u) ? (u & 0x7FFFFFFFu) : ~u;
    return __uint_as_float(b);
}

__device__ __forceinline__ unsigned pack4_fp8(float a, float b, float c, float d) {
    int r = __builtin_amdgcn_cvt_pk_fp8_f32(a, b, 0, false);   // bytes 0,1
    r = __builtin_amdgcn_cvt_pk_fp8_f32(c, d, r, true);        // bytes 2,3
    return (unsigned)r;
}

// ---------------- fused prep: norm (16 lanes/row) | proto | init_P ----------------
// Query rows -> fqn row-major [tr][96 words]. Shot rows -> fsnp in FRAGMENT order:
// word addr = bn*98304 + sh*49152 + chunk*3072 + ks*1024 + part*256 + hi*64 + l15*4 + w
// where (per j, lane-l16): ks=j>>1, part=(l16>>2)&1, hi=(j&1)*2+(l16>>3), w=l16&3.
__global__ void prep_kernel(const float* __restrict__ feat_query,
                            const float* __restrict__ feat_shot,
                            const float* __restrict__ x_shot,
                            unsigned* __restrict__ fqn,
                            unsigned* __restrict__ fsnp,
                            float* __restrict__ proto,
                            unsigned* __restrict__ P) {
    const int blk  = blockIdx.x;
    const int tid  = threadIdx.x;
    const int lane = tid & 63;
    const int wv   = tid >> 6;

    if (blk < 2478) {                       // ---- token L2 norm -> fp8, 4 rows/wave ----
        const int tr  = blk * 16 + wv * 4 + (lane >> 4);   // 0..39639
        const int l16 = lane & 15;
        if (tr >= 39640) return;

        const float* row;
        unsigned* o32;
        bool zero = false;
        bool shot = false;
        if (tr < 29400) {
            row = feat_query + (size_t)tr * 384;
            o32 = fqn + (size_t)tr * 96;
        } else {
            const int sp = tr - 29400;          // padded shot row: [bn][1024]
            const int bn = sp >> 10;
            const int s  = sp & 1023;           // col within class block
            row  = feat_shot + ((size_t)bn * 980 + s) * 384;
            zero = (s >= 980);
            shot = true;
            const int shh   = s >> 9;
            const int c     = s & 511;
            const int chunk = c >> 5;
            const int cl    = c & 31;
            o32 = fsnp + (size_t)bn * 98304 + shh * 49152 + chunk * 3072
                       + (cl >> 4) * 512 + (cl & 15) * 4;
        }
        // per-j store index (fragment order for shot, row-major for query)
        int idxs[6];
#pragma unroll
        for (int j = 0; j < 6; ++j)
            idxs[j] = shot ? ((j >> 1) * 1024 + ((l16 >> 2) & 1) * 256
                              + (((j & 1) << 1) + (l16 >> 3)) * 64 + (l16 & 3))
                           : (l16 + 16 * j);

        if (zero) {
#pragma unroll
            for (int j = 0; j < 6; ++j) o32[idxs[j]] = 0u;
            return;
        }
        const float4* rf4 = (const float4*)row;
        float4 v[6];
        float ss = 0.f;
#pragma unroll
        for (int j = 0; j < 6; ++j) {
            v[j] = rf4[l16 + 16 * j];
            ss += v[j].x * v[j].x + v[j].y * v[j].y + v[j].z * v[j].z + v[j].w * v[j].w;
        }
#pragma unroll
        for (int off = 1; off < 16; off <<= 1) ss += __shfl_xor(ss, off, 64);
        const float sc = 1.0f / fmaxf(sqrtf(ss), 1e-8f);
#pragma unroll
        for (int j = 0; j < 6; ++j)
            o32[idxs[j]] = pack4_fp8(v[j].x * sc, v[j].y * sc, v[j].z * sc, v[j].w * sc);
    } else if (blk < 2481) {                // ---- proto = l2norm(mean_k x_shot), fp32 ----
        const int gw = (blk - 2478) * 4 + wv;
        if (gw >= 10) return;
        const float* base = x_shot + (size_t)gw * 5 * 384;
        float v[6];
        float ss = 0.f;
#pragma unroll
        for (int j = 0; j < 6; ++j) {
            float s = 0.f;
#pragma unroll
            for (int kk = 0; kk < 5; ++kk) s += base[kk * 384 + lane + 64 * j];
            s *= 0.2f;
            v[j] = s;
            ss += s * s;
        }
#pragma unroll
        for (int off = 1; off < 64; off <<= 1) ss += __shfl_xor(ss, off, 64);
        const float scale = 1.0f / fmaxf(sqrtf(ss), 1e-12f);
#pragma unroll
        for (int j = 0; j < 6; ++j) proto[(size_t)gw * 384 + lane + 64 * j] = v[j] * scale;
    } else {                                // ---- init P to encoded -inf (0) ----
        const int i = (blk - 2481) * 256 + tid;
        if (i < 147000) P[i] = 0u;
    }
}

// ---------------- fp8 GEMM + row-max: 256 A-rows in regs, B depth-3 pipelined ----------------
// grid = 1160 blocks; 256 thr = 4 waves (64 rows each). XCD-chunked ordering (header).
// No LDS, no barriers. B fragments stream from the fragment-ordered fsnp (coalesced
// 1KB dwordx4 loads) through a rolling 3-slot register pipeline: slot ks holds k-step
// kglob with kglob%3==ks; after the 8 MFMAs of k-step kglob, the slot is re-issued for
// kglob+3 (WAR on the same regs keeps pressure flat; all indices compile-time).
__global__ __launch_bounds__(256, 2) void gemm_kernel(const uint8_t* __restrict__ fqn,
                                                      const uint8_t* __restrict__ fsnp,
                                                      unsigned* __restrict__ P) {
    // ---- XCD-chunked bijective decode: p -> w = (b*58+mt)*10 + (cls*2+sh) ----
    const int p   = blockIdx.x;             // 1160 = 8 chunks x 145
    const int w   = (p & 7) * 145 + (p >> 3);
    const int b   = w / 580;
    const int rem = w - b * 580;
    const int mt  = rem / 10;
    const int g   = rem - mt * 10;
    const int sh  = g & 1;
    const int bc  = b * 5 + (g >> 1);       // b*5+cls
    const int m0  = mt * 256;

    const int tid  = threadIdx.x;
    const int lane = tid & 63;
    const int wv   = tid >> 6;
    const int l15  = lane & 15;
    const int hi   = lane >> 4;

    const uint8_t* Ag = fqn  + (size_t)b * 14700 * 384;
    const uint8_t* Bg = fsnp + (size_t)bc * 393216 + (size_t)sh * 196608;
    const uint8_t* bp = Bg + lane * 16;    // + kglob*4096 + j*1024

    // ---- A fragments -> registers (one-time; wave wv holds rows m0+wv*64 .. +63) ----
    int8v A[4][3];
#pragma unroll
    for (int mi = 0; mi < 4; ++mi) {
        int row = m0 + wv * 64 + mi * 16 + l15;
        row = row < 14700 ? row : 14699;           // clamp; dead rows masked at epilogue
        const uint8_t* pa = Ag + (size_t)row * 384 + hi * 32;
#pragma unroll
        for (int ks = 0; ks < 3; ++ks) {
            const uint4 x = *(const uint4*)(pa + ks * 128);
            const uint4 y = *(const uint4*)(pa + ks * 128 + 16);
            A[mi][ks] = (int8v){(int)x.x, (int)x.y, (int)x.z, (int)x.w,
                                (int)y.x, (int)y.y, (int)y.z, (int)y.w};
        }
    }

    float rmax[4][4];
#pragma unroll
    for (int mi = 0; mi < 4; ++mi)
#pragma unroll
        for (int i = 0; i < 4; ++i) rmax[mi][i] = -3.0e38f;

    // ---- prologue: fill the 3-slot pipeline with k-steps 0,1,2 ----
    uint4 S[3][4];                          // statically indexed only
#pragma unroll
    for (int ks = 0; ks < 3; ++ks) {
        const uint8_t* p2 = bp + (size_t)ks * 4096;
#pragma unroll
        for (int j = 0; j < 4; ++j)
            S[ks][j] = *(const uint4*)(p2 + j * 1024);
    }

    for (int chunk = 0; chunk < 16; ++chunk) {
        f32x4 acc[4][2];
#pragma unroll
        for (int mi = 0; mi < 4; ++mi)
#pragma unroll
            for (int nf = 0; nf < 2; ++nf) acc[mi][nf] = (f32x4){0.f, 0.f, 0.f, 0.f};

#pragma unroll
        for (int ks = 0; ks < 3; ++ks) {
            // consume slot ks (k-step chunk*3+ks; chunk*3+ks ≡ ks mod 3)
            const int8v Bf0 = (int8v){(int)S[ks][0].x, (int)S[ks][0].y,
                                      (int)S[ks][0].z, (int)S[ks][0].w,
                                      (int)S[ks][1].x, (int)S[ks][1].y,
                                      (int)S[ks][1].z, (int)S[ks][1].w};
            const int8v Bf1 = (int8v){(int)S[ks][2].x, (int)S[ks][2].y,
                                      (int)S[ks][2].z, (int)S[ks][2].w,
                                      (int)S[ks][3].x, (int)S[ks][3].y,
                                      (int)S[ks][3].z, (int)S[ks][3].w};
#pragma unroll
            for (int mi = 0; mi < 4; ++mi) {
                acc[mi][0] = __builtin_amdgcn_mfma_scale_f32_16x16x128_f8f6f4(
                    A[mi][ks], Bf0, acc[mi][0],
                    0, 0, 0, 0x7F7F7F7F, 0, 0x7F7F7F7F);
                acc[mi][1] = __builtin_amdgcn_mfma_scale_f32_16x16x128_f8f6f4(
                    A[mi][ks], Bf1, acc[mi][1],
                    0, 0, 0, 0x7F7F7F7F, 0, 0x7F7F7F7F);
            }
            // re-issue slot ks for k-step chunk*3+ks+3 (clamped tail; issue->use
            // window = 2 full k-steps of MFMA >= loaded L2 latency)
            {
                const int kn = chunk * 3 + ks + 3;
                const int kc = kn < 48 ? kn : 47;
                const uint8_t* p2 = bp + (size_t)kc * 4096;
#pragma unroll
                for (int j = 0; j < 4; ++j)
                    S[ks][j] = *(const uint4*)(p2 + j * 1024);
            }
        }

        // fold row-max (mask padded cols >= 980; only sh=1 late chunks can fail)
#pragma unroll
        for (int nf = 0; nf < 2; ++nf) {
            if (sh * 512 + chunk * 32 + nf * 16 + l15 < 980) {
#pragma unroll
                for (int mi = 0; mi < 4; ++mi)
#pragma unroll
                    for (int i = 0; i < 4; ++i)
                        rmax[mi][i] = fmaxf(rmax[mi][i], acc[mi][nf][i]);
            }
        }
    }

    // ---- epilogue: max over the 16 col-lanes, then device-scope atomicMax ----
#pragma unroll
    for (int mi = 0; mi < 4; ++mi)
#pragma unroll
        for (int i = 0; i < 4; ++i) {
            float v = rmax[mi][i];
#pragma unroll
            for (int off = 1; off < 16; off <<= 1) v = fmaxf(v, __shfl_xor(v, off, 64));
            if (l15 == 0) {
                const int row = m0 + wv * 64 + mi * 16 + hi * 4 + i;
                if (row < 14700)
                    atomicMax(&P[(size_t)bc * 14700 + row], enc_f(v));
            }
        }
}

// ---------------- fused final: logits (mean over t of row maxima) | cls_logits ----------------
__global__ void final_kernel(const unsigned* __restrict__ P,
                             const float* __restrict__ xq,
                             const float* __restrict__ proto,
                             float* __restrict__ out) {
    const int blk  = blockIdx.x;
    const int tid  = threadIdx.x;
    const int lane = tid & 63;
    const int wv   = tid >> 6;

    if (blk < 188) {                        // ---- logits ----
        const int gw = blk * 4 + wv;        // (b*75+q)*5+n
        if (gw >= 750) return;
        const int n  = gw % 5;
        const int bq = gw / 5;
        const int b  = bq / 75;
        const int q  = bq % 75;
        const unsigned* row = P + (size_t)(b * 5 + n) * 14700 + q * 196;
        float s = 0.f;
        for (int t = lane; t < 196; t += 64) s += dec_f(row[t]);
#pragma unroll
        for (int off = 1; off < 64; off <<= 1) s += __shfl_xor(s, off, 64);
        if (lane == 0) out[gw] = s * (1.0f / 196.0f);
    } else {                                // ---- cls_logits ----
        const int gw = (blk - 188) * 4 + wv;   // b*75+q
        if (gw >= 150) return;
        const float* row = xq + (size_t)gw * 384;
        float u[6];
        float ss = 0.f;
#pragma unroll
        for (int j = 0; j < 6; ++j) { u[j] = row[lane + 64 * j]; ss += u[j] * u[j]; }
#pragma unroll
        for (int off = 1; off < 64; off <<= 1) ss += __shfl_xor(ss, off, 64);
        const float scale = 1.0f / fmaxf(sqrtf(ss), 1e-12f);
#pragma unroll
        for (int j = 0; j < 6; ++j) u[j] *= scale;
        const int b = gw / 75;
        for (int n = 0; n < 5; ++n) {
            const float* p = proto + (size_t)(b * 5 + n) * 384;
            float d = 0.f;
#pragma unroll
            for (int j = 0; j < 6; ++j) d += u[j] * p[lane + 64 * j];
#pragma unroll
            for (int off = 1; off < 64; off <<= 1) d += __shfl_xor(d, off, 64);
            if (lane == 0) out[750 + gw * 5 + n] = 10.0f * d;
        }
    }
}

extern "C" void kernel_launch(void* const* d_in, const int* in_sizes, int n_in,
                              void* d_out, int out_size, void* d_ws, size_t ws_size,
                              hipStream_t stream) {
    const float* feat_shot  = (const float*)d_in[0];  // [2,5,5,196,384]
    const float* feat_query = (const float*)d_in[1];  // [2,75,196,384]
    const float* x_shot     = (const float*)d_in[2];  // [2,5,5,384]
    const float* x_query    = (const float*)d_in[3];  // [2,75,384]
    float* out = (float*)d_out;
    char* ws = (char*)d_ws;

    // ws layout (15.8 MiB total)
    uint8_t*  fqn   = (uint8_t*)ws;                     // 29400*384  = 11,289,600 B (fp8, row-major)
    uint8_t*  fsnp  = (uint8_t*)(ws + 11289600);        // 10240*384  =  3,932,160 B (fp8, FRAGMENT order)
    float*    proto = (float*)(ws + 15221760);          //      3,840 f32
    unsigned* P     = (unsigned*)(ws + 15237120);       //    147,000 u32

    prep_kernel<<<3056, 256, 0, stream>>>(feat_query, feat_shot, x_shot,
                                          (unsigned*)fqn, (unsigned*)fsnp, proto, P);
    gemm_kernel<<<1160, 256, 0, stream>>>(fqn, fsnp, P);
    final_kernel<<<226, 256, 0, stream>>>(P, x_query, proto, out);
}